// Round 5
// baseline (9658.190 us; speedup 1.0000x reference)
//
#include <hip/hip_runtime.h>
#include <math.h>

// Exact k-th order statistic + mask, fp32, n = 64*1024*1024.
// Sampled-bracket single-full-pass design with exact verification and an
// always-enqueued flag-gated fallback (proven 3-pass radix select).
//
// state slots:
//  [0]=lo_bin [1]=hi_bin [2]=C_hi [3]=flag [4]=r' (cand rank)
//  [5]=bA [6]=rA [7]=b_low [8]=scratch [9]=fb thr bits
//  [10]=fb b1 [11]=fb r2 [12]=fb b2 [13]=fb r3 [14]=fb b3 [15]=fb junk

#define N_STATE   16
#define SAMP_OFF  16
#define CANDA_OFF (SAMP_OFF + 4096)
#define CANDB_OFF (CANDA_OFF + 65536)
#define CNT_OFF   (CANDB_OFF + 65536)
#define NWAVES    8192
#define FB1_OFF   (CNT_OFF + NWAVES)
#define FB2_OFF   (FB1_OFF + 4096)
#define FB3_OFF   (FB2_OFF + 4096)
#define FIXED_Z   (FB3_OFF + 256)     // ints zeroed every call (~575 KB)
#define CAND_OFF  FIXED_Z
#define SEG       2048u

// small-ws fallback layout (standalone proven path)
#define FB_WS_INTS (16 + 4096 + 4096 + 256)

typedef float vfloat4 __attribute__((ext_vector_type(4)));

__device__ __forceinline__ unsigned map_bits(unsigned raw) {
    return (raw & 0x80000000u) ? ~raw : (raw | 0x80000000u);
}

// ---------------- sample histogram (12-bit) ----------------
// 512 blocks x 256 thr = 131072 threads; thread t reads uint4 #(t>>2)*512+(t&3)
// -> 4 consecutive uint4 (one 64B line) per 512-uint4 window; S = 524288 elems.
__global__ void __launch_bounds__(256)
sample_hist(const uint4* __restrict__ x, int n4, unsigned* __restrict__ hist)
{
    __shared__ unsigned lh[4096];
    for (int i = threadIdx.x; i < 4096; i += 256) lh[i] = 0u;
    __syncthreads();
    int t = blockIdx.x * 256 + threadIdx.x;
    int idx = (t >> 2) * 512 + (t & 3);
    if (idx < n4) {
        uint4 v = x[idx];
        atomicAdd(&lh[map_bits(v.x) >> 20], 1u);
        atomicAdd(&lh[map_bits(v.y) >> 20], 1u);
        atomicAdd(&lh[map_bits(v.z) >> 20], 1u);
        atomicAdd(&lh[map_bits(v.w) >> 20], 1u);
    }
    __syncthreads();
    for (int i = threadIdx.x; i < 4096; i += 256) {
        unsigned c = lh[i];
        if (c) atomicAdd(&hist[i], c);
    }
}

// ---------------- bracket from sample CDF ----------------
__global__ void __launch_bounds__(1024)
bracket(const unsigned* __restrict__ samp, unsigned RLO, unsigned RHI,
        unsigned* __restrict__ st)
{
    __shared__ unsigned s[1024];
    __shared__ unsigned sh_lo, sh_hi;
    int t = threadIdx.x;
    if (t == 0) { sh_lo = 0u; sh_hi = 4096u; }
    __syncthreads();
    unsigned v0 = samp[4*t], v1 = samp[4*t+1], v2 = samp[4*t+2], v3 = samp[4*t+3];
    unsigned my = v0 + v1 + v2 + v3;
    s[t] = my;
    __syncthreads();
    for (int off = 1; off < 1024; off <<= 1) {
        unsigned w = (t >= off) ? s[t - off] : 0u;
        __syncthreads();
        s[t] += w;
        __syncthreads();
    }
    unsigned excl = s[t] - my;
    unsigned c0 = excl, c1 = excl + v0, c2 = c1 + v1, c3 = c2 + v2;
    unsigned cb[4] = {c0, c1, c2, c3};
    #pragma unroll
    for (int j = 0; j < 4; ++j) {
        unsigned b = (unsigned)(4*t + j);
        if (cb[j] <= RLO) atomicMax(&sh_lo, b);
        if (cb[j] >= RHI) atomicMin(&sh_hi, b);
    }
    __syncthreads();
    if (t == 0) { st[0] = sh_lo; st[1] = sh_hi; }
}

// ---------------- the single full pass ----------------
__global__ void __launch_bounds__(256)
pass2(const uint4* __restrict__ x, int n4, vfloat4* __restrict__ out,
      unsigned* __restrict__ candA, uint2* __restrict__ cand,
      unsigned* __restrict__ cntw, unsigned* __restrict__ st)
{
    const unsigned lo = st[0], hi = st[1];
    const unsigned lane = threadIdx.x & 63u;
    const unsigned wave = (unsigned)(blockIdx.x * 256 + threadIdx.x) >> 6;
    uint2* seg = cand + (size_t)wave * SEG;
    unsigned ccnt = 0;     // wave-uniform candidate count
    unsigned chi  = 0;     // per-lane count of (bin >= hi)

    int idx = blockIdx.x * 256 + threadIdx.x;
    int stride = gridDim.x * 256;
    for (int i = idx; i < n4; i += stride) {
        uint4 v = x[i];
        vfloat4 o;
        unsigned gi = (unsigned)i * 4u;
        #define STEP(COMP, OFS) { \
            unsigned u = map_bits(v.COMP); unsigned p = u >> 20; \
            bool ge = (p >= hi); chi += ge ? 1u : 0u; \
            o[OFS] = ge ? 1.0f : 0.0f; \
            bool c = (p >= lo) && !ge; \
            if (c) atomicAdd(&candA[u >> 16], 1u); \
            unsigned long long m = __ballot(c); \
            if (c) { unsigned pos = ccnt + (unsigned)__popcll(m & ((1ull << lane) - 1ull)); \
                     if (pos < SEG) seg[pos] = make_uint2(u, gi + OFS); } \
            ccnt += (unsigned)__popcll(m); }
        STEP(x, 0u) STEP(y, 1u) STEP(z, 2u) STEP(w, 3u)
        #undef STEP
        __builtin_nontemporal_store(o, &out[i]);
    }
    for (int off = 32; off > 0; off >>= 1) chi += __shfl_down(chi, off, 64);
    if (lane == 0) {
        cntw[wave] = ccnt;                 // raw (uncapped) for overflow check
        atomicAdd(&st[2], chi);
    }
}

// ---------------- exact bracket verification ----------------
__global__ void __launch_bounds__(1024)
flagcomp(const unsigned* __restrict__ cntw, unsigned n, unsigned r,
         unsigned* __restrict__ st)
{
    __shared__ unsigned ssum[1024];
    __shared__ unsigned smax[1024];
    int t = threadIdx.x;
    unsigned sum = 0, mx = 0;
    for (int i = t; i < NWAVES; i += 1024) {
        unsigned c = cntw[i];
        sum += c; mx = (c > mx) ? c : mx;
    }
    ssum[t] = sum; smax[t] = mx;
    __syncthreads();
    for (int off = 512; off > 0; off >>= 1) {
        if (t < off) {
            ssum[t] += ssum[t + off];
            smax[t] = (smax[t + off] > smax[t]) ? smax[t + off] : smax[t];
        }
        __syncthreads();
    }
    if (t == 0) {
        unsigned long long Nc  = ssum[0];
        unsigned long long Chi = st[2];
        unsigned long long Nlt_hi = (unsigned long long)n - Chi;
        unsigned flag = 0;
        if (smax[0] > SEG) flag = 1;
        if (Nc > Nlt_hi)   flag = 1;
        unsigned long long Nlt_lo = (Nc > Nlt_hi) ? 0ull : (Nlt_hi - Nc);
        if (!((Nlt_lo <= (unsigned long long)r) && ((unsigned long long)r < Nlt_hi)))
            flag = 1;
        st[3] = flag;
        st[4] = (unsigned)((unsigned long long)r - Nlt_lo);
    }
}

// ---------------- generic gated single-block select ----------------
__global__ void __launch_bounds__(1024)
scan_select(const unsigned* __restrict__ hist, int nbins,
            const unsigned* __restrict__ rank_in, unsigned rank_imm,
            unsigned* __restrict__ bin_out, unsigned* __restrict__ rank_out,
            const unsigned* __restrict__ gate, int want_nonzero)
{
    if (gate) {
        unsigned g = *gate;
        if ((g != 0u) != (want_nonzero != 0)) return;
    }
    __shared__ unsigned s[1024];
    int t = threadIdx.x;
    unsigned rank = rank_in ? *rank_in : rank_imm;
    int per = (nbins + 1023) >> 10;
    int base = t * per;
    unsigned mySum = 0;
    for (int i = 0; i < per; ++i) {
        int b = base + i;
        if (b < nbins) mySum += hist[b];
    }
    s[t] = mySum;
    __syncthreads();
    for (int off = 1; off < 1024; off <<= 1) {
        unsigned v = (t >= off) ? s[t - off] : 0u;
        __syncthreads();
        s[t] += v;
        __syncthreads();
    }
    unsigned incl = s[t];
    unsigned excl = incl - mySum;
    if (rank >= excl && rank < incl) {
        unsigned run = excl;
        for (int i = 0; i < per; ++i) {
            int b = base + i;
            unsigned c = (b < nbins) ? hist[b] : 0u;
            if (rank < run + c) { *bin_out = (unsigned)b; *rank_out = rank - run; break; }
            run += c;
        }
    }
}

// ---------------- candidate low-16 histogram ----------------
__global__ void __launch_bounds__(256)
candb_hist(const uint2* __restrict__ cand, const unsigned* __restrict__ cntw,
           const unsigned* __restrict__ st, unsigned* __restrict__ candB)
{
    if (st[3] != 0u) return;
    unsigned bA = st[5];
    unsigned lane = threadIdx.x & 63u;
    unsigned wave = (unsigned)(blockIdx.x * 256 + threadIdx.x) >> 6;  // 2048 waves
    for (int k = 0; k < 4; ++k) {
        unsigned sidx = wave * 4u + (unsigned)k;
        const uint2* seg = cand + (size_t)sidx * SEG;
        unsigned m = cntw[sidx]; if (m > SEG) m = SEG;
        for (unsigned j = lane; j < m; j += 64u) {
            uint2 cv = seg[j];
            if ((cv.x >> 16) == bA) atomicAdd(&candB[cv.x & 0xFFFFu], 1u);
        }
    }
}

// ---------------- fixup ----------------
__global__ void __launch_bounds__(256)
fixup(const uint2* __restrict__ cand, const unsigned* __restrict__ cntw,
      const unsigned* __restrict__ st, float* __restrict__ out)
{
    if (st[3] != 0u) return;
    unsigned thr = (st[5] << 16) | st[7];
    unsigned lane = threadIdx.x & 63u;
    unsigned wave = (unsigned)(blockIdx.x * 256 + threadIdx.x) >> 6;
    const uint2* seg = cand + (size_t)wave * SEG;
    unsigned m = cntw[wave]; if (m > SEG) m = SEG;
    for (unsigned j = lane; j < m; j += 64u) {
        uint2 cv = seg[j];
        if (cv.x >= thr) out[cv.y] = 1.0f;
    }
}

// ---------------- fallback (proven 3-pass radix), flag-gated ----------------
__global__ void __launch_bounds__(256)
hist_pass(const uint4* __restrict__ x, int n4, int shift, int nbins, int mode,
          const unsigned* __restrict__ state, unsigned* __restrict__ hist,
          const unsigned* __restrict__ gate)
{
    if (gate && *gate == 0u) return;
    __shared__ unsigned lh[4096];
    for (int i = threadIdx.x; i < nbins; i += blockDim.x) lh[i] = 0u;
    __syncthreads();

    unsigned tgt = 0; int mshift = 0;
    if (mode == 1)      { tgt = state[0];                      mshift = 20; }
    else if (mode == 2) { tgt = (state[0] << 12) | state[2];   mshift = 8;  }

    const unsigned binmask = (unsigned)(nbins - 1);
    int idx = blockIdx.x * blockDim.x + threadIdx.x;
    int stride = gridDim.x * blockDim.x;
    for (int i = idx; i < n4; i += stride) {
        uint4 v = x[i];
        unsigned u;
        u = map_bits(v.x); if (!mode || (u >> mshift) == tgt) atomicAdd(&lh[(u >> shift) & binmask], 1u);
        u = map_bits(v.y); if (!mode || (u >> mshift) == tgt) atomicAdd(&lh[(u >> shift) & binmask], 1u);
        u = map_bits(v.z); if (!mode || (u >> mshift) == tgt) atomicAdd(&lh[(u >> shift) & binmask], 1u);
        u = map_bits(v.w); if (!mode || (u >> mshift) == tgt) atomicAdd(&lh[(u >> shift) & binmask], 1u);
    }
    __syncthreads();
    for (int i = threadIdx.x; i < nbins; i += blockDim.x) {
        unsigned c = lh[i];
        if (c) atomicAdd(&hist[i], c);
    }
}

__global__ void finalize_thr_fb(unsigned* st, const unsigned* gate) {
    if (gate && *gate == 0u) return;
    unsigned u = (st[10] << 20) | (st[12] << 8) | st[14];
    st[9] = (u & 0x80000000u) ? (u & 0x7FFFFFFFu) : ~u;
}

__global__ void __launch_bounds__(256)
mask_kernel(const float4* __restrict__ x, float4* __restrict__ out, int n4,
            const unsigned* __restrict__ st, const unsigned* __restrict__ gate)
{
    if (gate && *gate == 0u) return;
    float thr = __uint_as_float(st[9]);
    int idx = blockIdx.x * blockDim.x + threadIdx.x;
    int stride = gridDim.x * blockDim.x;
    for (int i = idx; i < n4; i += stride) {
        float4 v = x[i];
        float4 o;
        o.x = (v.x >= thr) ? 1.0f : 0.0f;
        o.y = (v.y >= thr) ? 1.0f : 0.0f;
        o.z = (v.z >= thr) ? 1.0f : 0.0f;
        o.w = (v.w >= thr) ? 1.0f : 0.0f;
        out[i] = o;
    }
}

// ---------------- host ----------------
extern "C" void kernel_launch(void* const* d_in, const int* in_sizes, int n_in,
                              void* d_out, int out_size, void* d_ws, size_t ws_size,
                              hipStream_t stream)
{
    const float* x = (const float*)d_in[0];
    float* out = (float*)d_out;
    long long n = (long long)in_sizes[0];
    long long k = (long long)((double)n * 0.9);   // matches Python int(n * RATIO)

    if (k <= 0) {
        hipMemsetAsync(d_out, 0, (size_t)out_size * sizeof(float), stream);
        return;
    }

    unsigned* ws = (unsigned*)d_ws;
    unsigned* st = ws;
    int n4 = (int)(n / 4);
    const uint4* x4 = (const uint4*)x;
    unsigned r = (unsigned)(n - k);               // ascending rank of threshold

    size_t need_fast = (size_t)CAND_OFF * 4 + (size_t)NWAVES * SEG * 8;

    if (ws_size >= need_fast) {
        unsigned* samp  = ws + SAMP_OFF;
        unsigned* candA = ws + CANDA_OFF;
        unsigned* candB = ws + CANDB_OFF;
        unsigned* cntw  = ws + CNT_OFF;
        unsigned* fb1   = ws + FB1_OFF;
        unsigned* fb2   = ws + FB2_OFF;
        unsigned* fb3   = ws + FB3_OFF;
        uint2*    cand  = (uint2*)(ws + CAND_OFF);

        const unsigned S = 524288u;
        double T = (double)r / (double)n;
        const double EPS = 0.005;
        double tlo = T - EPS; if (tlo < 0.0) tlo = 0.0;
        double thi = T + EPS; if (thi > 1.0) thi = 1.0;
        unsigned RLO = (unsigned)floor(tlo * (double)S);
        unsigned RHI = (unsigned)ceil(thi * (double)S);
        if (RHI > S) RHI = S;

        hipMemsetAsync(d_ws, 0, (size_t)FIXED_Z * sizeof(unsigned), stream);

        sample_hist<<<512, 256, 0, stream>>>(x4, n4, samp);
        bracket<<<1, 1024, 0, stream>>>(samp, RLO, RHI, st);
        pass2<<<2048, 256, 0, stream>>>(x4, n4, (vfloat4*)out, candA, cand, cntw, st);
        flagcomp<<<1, 1024, 0, stream>>>(cntw, (unsigned)n, r, st);
        // fast-path select chain (gated on flag==0)
        scan_select<<<1, 1024, 0, stream>>>(candA, 65536, &st[4], 0u, &st[5], &st[6], &st[3], 0);
        candb_hist<<<512, 256, 0, stream>>>(cand, cntw, st, candB);
        scan_select<<<1, 1024, 0, stream>>>(candB, 65536, &st[6], 0u, &st[7], &st[8], &st[3], 0);
        fixup<<<2048, 256, 0, stream>>>(cand, cntw, st, out);
        // fallback chain (gated on flag!=0) — proven exact path
        hist_pass<<<2048, 256, 0, stream>>>(x4, n4, 20, 4096, 0, &st[10], fb1, &st[3]);
        scan_select<<<1, 1024, 0, stream>>>(fb1, 4096, nullptr, r, &st[10], &st[11], &st[3], 1);
        hist_pass<<<2048, 256, 0, stream>>>(x4, n4, 8, 4096, 1, &st[10], fb2, &st[3]);
        scan_select<<<1, 1024, 0, stream>>>(fb2, 4096, &st[11], 0u, &st[12], &st[13], &st[3], 1);
        hist_pass<<<2048, 256, 0, stream>>>(x4, n4, 0, 256, 2, &st[10], fb3, &st[3]);
        scan_select<<<1, 1024, 0, stream>>>(fb3, 256, &st[13], 0u, &st[14], &st[15], &st[3], 1);
        finalize_thr_fb<<<1, 1, 0, stream>>>(st, &st[3]);
        mask_kernel<<<2048, 256, 0, stream>>>((const float4*)x, (float4*)out, n4, st, &st[3]);
    } else {
        // small-ws standalone fallback: 3-pass radix + mask (ungated)
        unsigned* h1 = ws + 16;
        unsigned* h2 = ws + 16 + 4096;
        unsigned* h3 = ws + 16 + 8192;

        hipMemsetAsync(d_ws, 0, FB_WS_INTS * sizeof(unsigned), stream);

        hist_pass<<<2048, 256, 0, stream>>>(x4, n4, 20, 4096, 0, &ws[10], h1, nullptr);
        scan_select<<<1, 1024, 0, stream>>>(h1, 4096, nullptr, r, &ws[10], &ws[11], nullptr, 0);
        hist_pass<<<2048, 256, 0, stream>>>(x4, n4, 8, 4096, 1, &ws[10], h2, nullptr);
        scan_select<<<1, 1024, 0, stream>>>(h2, 4096, &ws[11], 0u, &ws[12], &ws[13], nullptr, 0);
        hist_pass<<<2048, 256, 0, stream>>>(x4, n4, 0, 256, 2, &ws[10], h3, nullptr);
        scan_select<<<1, 1024, 0, stream>>>(h3, 256, &ws[13], 0u, &ws[14], &ws[15], nullptr, 0);
        finalize_thr_fb<<<1, 1, 0, stream>>>(ws, nullptr);
        mask_kernel<<<2048, 256, 0, stream>>>((const float4*)x, (float4*)out, n4, ws, nullptr);
    }
}

// Round 6
// 258.915 us; speedup vs baseline: 37.3026x; 37.3026x over previous
//
#include <hip/hip_runtime.h>
#include <math.h>

// Exact k-th order statistic + mask, fp32, n = 64*1024*1024.
// Sampled-bracket single-full-pass design. Refine histogram keyed on LOW
// mantissa bits (uniform -> contention-free atomics). Exact verification +
// always-enqueued flag-gated fallback (proven 3-pass radix select).
//
// state: [0]=lo [1]=hi [2]=C_hi [3]=flag [4]=r' [5]=chunkA [6]=rA [7]=binB
//        [8]=junk [9]=fb_thr [10..15]=fb chain

#define ST_OFF    0
#define SAMP_OFF  16
#define FB1_OFF   (16 + 4096)
#define FB2_OFF   (FB1_OFF + 4096)
#define FB3_OFF   (FB2_OFF + 4096)
#define HREF_OFF  (FB3_OFF + 256)
#define HREF_INTS (4 * 1048576)                 // 4M bins: (p-lo)<4 x low-20
#define FIXED_Z   (HREF_OFF + HREF_INTS)        // zeroed every call (~16.8 MB)
#define PART_OFF  FIXED_Z                       // 4096 chunk partials
#define CNT_OFF   (PART_OFF + 4096)             // 8192 per-wave counts
#define CAND_OFF  (CNT_OFF + 8192)
#define NWAVES    8192
#define SEG       2048u

#define FB_WS_INTS (16 + 4096 + 4096 + 256)

typedef float vfloat4 __attribute__((ext_vector_type(4)));

__device__ __forceinline__ unsigned map_bits(unsigned raw) {
    return (raw & 0x80000000u) ? ~raw : (raw | 0x80000000u);
}

// ---------------- workspace zeroing (replaces hipMemsetAsync) ----------------
__global__ void __launch_bounds__(256)
zero_ws(uint4* __restrict__ p, int n16)
{
    int i = blockIdx.x * 256 + threadIdx.x;
    int s = gridDim.x * 256;
    uint4 z = make_uint4(0u, 0u, 0u, 0u);
    for (; i < n16; i += s) p[i] = z;
}

// ---------------- sample histogram (12-bit), S = 524288 elems ----------------
__global__ void __launch_bounds__(256)
sample_hist(const uint4* __restrict__ x, int n4, unsigned* __restrict__ hist)
{
    __shared__ unsigned lh[4096];
    for (int i = threadIdx.x; i < 4096; i += 256) lh[i] = 0u;
    __syncthreads();
    int t = blockIdx.x * 256 + threadIdx.x;
    int idx = (t >> 2) * 512 + (t & 3);
    if (idx < n4) {
        uint4 v = x[idx];
        atomicAdd(&lh[map_bits(v.x) >> 20], 1u);
        atomicAdd(&lh[map_bits(v.y) >> 20], 1u);
        atomicAdd(&lh[map_bits(v.z) >> 20], 1u);
        atomicAdd(&lh[map_bits(v.w) >> 20], 1u);
    }
    __syncthreads();
    for (int i = threadIdx.x; i < 4096; i += 256) {
        unsigned c = lh[i];
        if (c) atomicAdd(&hist[i], c);
    }
}

// ---------------- bracket from sample CDF (span clamped to 4) ----------------
__global__ void __launch_bounds__(1024)
bracket(const unsigned* __restrict__ samp, unsigned RLO, unsigned RHI,
        unsigned* __restrict__ st)
{
    __shared__ unsigned s[1024];
    __shared__ unsigned sh_lo, sh_hi;
    int t = threadIdx.x;
    if (t == 0) { sh_lo = 0u; sh_hi = 4096u; }
    __syncthreads();
    unsigned v0 = samp[4*t], v1 = samp[4*t+1], v2 = samp[4*t+2], v3 = samp[4*t+3];
    unsigned my = v0 + v1 + v2 + v3;
    s[t] = my;
    __syncthreads();
    for (int off = 1; off < 1024; off <<= 1) {
        unsigned w = (t >= off) ? s[t - off] : 0u;
        __syncthreads();
        s[t] += w;
        __syncthreads();
    }
    unsigned excl = s[t] - my;
    unsigned cb[4] = {excl, excl + v0, excl + v0 + v1, excl + v0 + v1 + v2};
    #pragma unroll
    for (int j = 0; j < 4; ++j) {
        unsigned b = (unsigned)(4*t + j);
        if (cb[j] <= RLO) atomicMax(&sh_lo, b);
        if (cb[j] >= RHI) atomicMin(&sh_hi, b);
    }
    __syncthreads();
    if (t == 0) {
        unsigned L = sh_lo, H = sh_hi;
        if (H > L + 4u) H = L + 4u;      // clamp; exact verification catches misses
        st[0] = L; st[1] = H;
    }
}

// ---------------- the single full pass ----------------
__global__ void __launch_bounds__(256)
pass2(const uint4* __restrict__ x, int n4, vfloat4* __restrict__ out,
      unsigned* __restrict__ href, uint2* __restrict__ cand,
      unsigned* __restrict__ cntw, unsigned* __restrict__ st)
{
    const unsigned lo = st[0], hi = st[1];
    const unsigned lane = threadIdx.x & 63u;
    const unsigned wave = (unsigned)(blockIdx.x * 256 + threadIdx.x) >> 6;
    uint2* seg = cand + (size_t)wave * SEG;
    unsigned ccnt = 0;     // wave-uniform candidate count
    unsigned chi  = 0;     // per-lane count of (bin >= hi)

    int idx = blockIdx.x * 256 + threadIdx.x;
    int stride = gridDim.x * 256;
    for (int i = idx; i < n4; i += stride) {
        uint4 v = x[i];
        vfloat4 o;
        unsigned gi = (unsigned)i * 4u;
        #define STEP(COMP, OFS) { \
            unsigned u = map_bits(v.COMP); unsigned p = u >> 20; \
            bool ge = (p >= hi); chi += ge ? 1u : 0u; \
            o[OFS] = ge ? 1.0f : 0.0f; \
            bool c = (p >= lo) && !ge; \
            if (c) atomicAdd(&href[((p - lo) << 20) | (u & 0xFFFFFu)], 1u); \
            unsigned long long m = __ballot(c); \
            if (c) { unsigned pos = ccnt + (unsigned)__popcll(m & ((1ull << lane) - 1ull)); \
                     if (pos < SEG) seg[pos] = make_uint2(u, gi + OFS); } \
            ccnt += (unsigned)__popcll(m); }
        STEP(x, 0u) STEP(y, 1u) STEP(z, 2u) STEP(w, 3u)
        #undef STEP
        __builtin_nontemporal_store(o, &out[i]);
    }
    for (int off = 32; off > 0; off >>= 1) chi += __shfl_down(chi, off, 64);
    if (lane == 0) {
        cntw[wave] = ccnt;                 // raw (uncapped) for overflow check
        atomicAdd(&st[2], chi);
    }
}

// ---------------- exact bracket verification ----------------
__global__ void __launch_bounds__(1024)
flagcomp(const unsigned* __restrict__ cntw, unsigned n, unsigned r,
         unsigned* __restrict__ st)
{
    __shared__ unsigned ssum[1024];
    __shared__ unsigned smax[1024];
    int t = threadIdx.x;
    unsigned sum = 0, mx = 0;
    for (int i = t; i < NWAVES; i += 1024) {
        unsigned c = cntw[i];
        sum += c; mx = (c > mx) ? c : mx;
    }
    ssum[t] = sum; smax[t] = mx;
    __syncthreads();
    for (int off = 512; off > 0; off >>= 1) {
        if (t < off) {
            ssum[t] += ssum[t + off];
            smax[t] = (smax[t + off] > smax[t]) ? smax[t + off] : smax[t];
        }
        __syncthreads();
    }
    if (t == 0) {
        unsigned long long Nc  = ssum[0];
        unsigned long long Chi = st[2];
        unsigned long long Nlt_hi = (unsigned long long)n - Chi;
        unsigned flag = 0;
        if (smax[0] > SEG) flag = 1;
        if (Nc > Nlt_hi)   flag = 1;
        unsigned long long Nlt_lo = (Nc > Nlt_hi) ? 0ull : (Nlt_hi - Nc);
        if (!((Nlt_lo <= (unsigned long long)r) && ((unsigned long long)r < Nlt_hi)))
            flag = 1;
        st[3] = flag;
        st[4] = (unsigned)((unsigned long long)r - Nlt_lo);
    }
}

// ---------------- refine-hist chunk reduction (gated) ----------------
__global__ void __launch_bounds__(256)
reduce_chunks(const unsigned* __restrict__ href, unsigned* __restrict__ part,
              const unsigned* __restrict__ gate)
{
    if (*gate != 0u) return;
    __shared__ unsigned s[256];
    unsigned sum = 0;
    int base = blockIdx.x * 1024;
    for (int t = threadIdx.x; t < 1024; t += 256) sum += href[base + t];
    s[threadIdx.x] = sum;
    __syncthreads();
    for (int off = 128; off > 0; off >>= 1) {
        if (threadIdx.x < off) s[threadIdx.x] += s[threadIdx.x + off];
        __syncthreads();
    }
    if (threadIdx.x == 0) part[blockIdx.x] = s[0];
}

// ---------------- generic gated single-block select ----------------
__global__ void __launch_bounds__(1024)
scan_select(const unsigned* __restrict__ hist, int nbins,
            const unsigned* __restrict__ chunk_sel, int chunk_mul,
            const unsigned* __restrict__ rank_in, unsigned rank_imm,
            unsigned* __restrict__ bin_out, unsigned* __restrict__ rank_out,
            const unsigned* __restrict__ gate, int want_nonzero)
{
    if (gate) {
        unsigned g = *gate;
        if ((g != 0u) != (want_nonzero != 0)) return;
    }
    __shared__ unsigned s[1024];
    int t = threadIdx.x;
    const unsigned* h = hist + (chunk_sel ? (size_t)(*chunk_sel) * (size_t)chunk_mul : 0);
    unsigned rank = rank_in ? *rank_in : rank_imm;
    int per = (nbins + 1023) >> 10;
    int base = t * per;
    unsigned mySum = 0;
    for (int i = 0; i < per; ++i) {
        int b = base + i;
        if (b < nbins) mySum += h[b];
    }
    s[t] = mySum;
    __syncthreads();
    for (int off = 1; off < 1024; off <<= 1) {
        unsigned v = (t >= off) ? s[t - off] : 0u;
        __syncthreads();
        s[t] += v;
        __syncthreads();
    }
    unsigned incl = s[t];
    unsigned excl = incl - mySum;
    if (rank >= excl && rank < incl) {
        unsigned run = excl;
        for (int i = 0; i < per; ++i) {
            int b = base + i;
            unsigned c = (b < nbins) ? h[b] : 0u;
            if (rank < run + c) { *bin_out = (unsigned)b; *rank_out = rank - run; break; }
            run += c;
        }
    }
}

// ---------------- fixup (gated) ----------------
__global__ void __launch_bounds__(256)
fixup(const uint2* __restrict__ cand, const unsigned* __restrict__ cntw,
      const unsigned* __restrict__ st, float* __restrict__ out)
{
    if (st[3] != 0u) return;
    unsigned key = st[5] * 1024u + st[7];
    unsigned thr = ((st[0] + (key >> 20)) << 20) | (key & 0xFFFFFu);
    unsigned lane = threadIdx.x & 63u;
    unsigned wave = (unsigned)(blockIdx.x * 256 + threadIdx.x) >> 6;
    const uint2* seg = cand + (size_t)wave * SEG;
    unsigned m = cntw[wave]; if (m > SEG) m = SEG;
    for (unsigned j = lane; j < m; j += 64u) {
        uint2 cv = seg[j];
        if (cv.x >= thr) out[cv.y] = 1.0f;
    }
}

// ---------------- fallback (proven 3-pass radix), flag-gated ----------------
__global__ void __launch_bounds__(256)
hist_pass(const uint4* __restrict__ x, int n4, int shift, int nbins, int mode,
          const unsigned* __restrict__ state, unsigned* __restrict__ hist,
          const unsigned* __restrict__ gate)
{
    if (gate && *gate == 0u) return;
    __shared__ unsigned lh[4096];
    for (int i = threadIdx.x; i < nbins; i += blockDim.x) lh[i] = 0u;
    __syncthreads();

    unsigned tgt = 0; int mshift = 0;
    if (mode == 1)      { tgt = state[0];                      mshift = 20; }
    else if (mode == 2) { tgt = (state[0] << 12) | state[2];   mshift = 8;  }

    const unsigned binmask = (unsigned)(nbins - 1);
    int idx = blockIdx.x * blockDim.x + threadIdx.x;
    int stride = gridDim.x * blockDim.x;
    for (int i = idx; i < n4; i += stride) {
        uint4 v = x[i];
        unsigned u;
        u = map_bits(v.x); if (!mode || (u >> mshift) == tgt) atomicAdd(&lh[(u >> shift) & binmask], 1u);
        u = map_bits(v.y); if (!mode || (u >> mshift) == tgt) atomicAdd(&lh[(u >> shift) & binmask], 1u);
        u = map_bits(v.z); if (!mode || (u >> mshift) == tgt) atomicAdd(&lh[(u >> shift) & binmask], 1u);
        u = map_bits(v.w); if (!mode || (u >> mshift) == tgt) atomicAdd(&lh[(u >> shift) & binmask], 1u);
    }
    __syncthreads();
    for (int i = threadIdx.x; i < nbins; i += blockDim.x) {
        unsigned c = lh[i];
        if (c) atomicAdd(&hist[i], c);
    }
}

__global__ void finalize_thr_fb(unsigned* st, const unsigned* gate) {
    if (gate && *gate == 0u) return;
    unsigned u = (st[10] << 20) | (st[12] << 8) | st[14];
    st[9] = (u & 0x80000000u) ? (u & 0x7FFFFFFFu) : ~u;
}

__global__ void __launch_bounds__(256)
mask_kernel(const float4* __restrict__ x, float4* __restrict__ out, int n4,
            const unsigned* __restrict__ st, const unsigned* __restrict__ gate)
{
    if (gate && *gate == 0u) return;
    float thr = __uint_as_float(st[9]);
    int idx = blockIdx.x * blockDim.x + threadIdx.x;
    int stride = gridDim.x * blockDim.x;
    for (int i = idx; i < n4; i += stride) {
        float4 v = x[i];
        float4 o;
        o.x = (v.x >= thr) ? 1.0f : 0.0f;
        o.y = (v.y >= thr) ? 1.0f : 0.0f;
        o.z = (v.z >= thr) ? 1.0f : 0.0f;
        o.w = (v.w >= thr) ? 1.0f : 0.0f;
        out[i] = o;
    }
}

// ---------------- host ----------------
extern "C" void kernel_launch(void* const* d_in, const int* in_sizes, int n_in,
                              void* d_out, int out_size, void* d_ws, size_t ws_size,
                              hipStream_t stream)
{
    const float* x = (const float*)d_in[0];
    float* out = (float*)d_out;
    long long n = (long long)in_sizes[0];
    long long k = (long long)((double)n * 0.9);   // matches Python int(n * RATIO)

    if (k <= 0) {
        hipMemsetAsync(d_out, 0, (size_t)out_size * sizeof(float), stream);
        return;
    }

    unsigned* ws = (unsigned*)d_ws;
    unsigned* st = ws;
    int n4 = (int)(n / 4);
    const uint4* x4 = (const uint4*)x;
    unsigned r = (unsigned)(n - k);               // ascending rank of threshold

    size_t need_fast = ((size_t)CAND_OFF + (size_t)NWAVES * SEG * 2) * 4;

    if (ws_size >= need_fast) {
        unsigned* samp = ws + SAMP_OFF;
        unsigned* fb1  = ws + FB1_OFF;
        unsigned* fb2  = ws + FB2_OFF;
        unsigned* fb3  = ws + FB3_OFF;
        unsigned* href = ws + HREF_OFF;
        unsigned* part = ws + PART_OFF;
        unsigned* cntw = ws + CNT_OFF;
        uint2*    cand = (uint2*)(ws + CAND_OFF);

        const unsigned S = 524288u;
        double T = (double)r / (double)n;
        const double EPS = 0.005;
        double tlo = T - EPS; if (tlo < 0.0) tlo = 0.0;
        double thi = T + EPS; if (thi > 1.0) thi = 1.0;
        unsigned RLO = (unsigned)floor(tlo * (double)S);
        unsigned RHI = (unsigned)ceil(thi * (double)S);
        if (RHI > S) RHI = S;

        zero_ws<<<1024, 256, 0, stream>>>((uint4*)d_ws, FIXED_Z / 4);
        sample_hist<<<512, 256, 0, stream>>>(x4, n4, samp);
        bracket<<<1, 1024, 0, stream>>>(samp, RLO, RHI, st);
        pass2<<<2048, 256, 0, stream>>>(x4, n4, (vfloat4*)out, href, cand, cntw, st);
        flagcomp<<<1, 1024, 0, stream>>>(cntw, (unsigned)n, r, st);
        // fast-path select chain (gated on flag==0)
        reduce_chunks<<<4096, 256, 0, stream>>>(href, part, &st[3]);
        scan_select<<<1, 1024, 0, stream>>>(part, 4096, nullptr, 0, &st[4], 0u, &st[5], &st[6], &st[3], 0);
        scan_select<<<1, 1024, 0, stream>>>(href, 1024, &st[5], 1024, &st[6], 0u, &st[7], &st[8], &st[3], 0);
        fixup<<<2048, 256, 0, stream>>>(cand, cntw, st, out);
        // fallback chain (gated on flag!=0) — proven exact path
        hist_pass<<<2048, 256, 0, stream>>>(x4, n4, 20, 4096, 0, &st[10], fb1, &st[3]);
        scan_select<<<1, 1024, 0, stream>>>(fb1, 4096, nullptr, 0, nullptr, r, &st[10], &st[11], &st[3], 1);
        hist_pass<<<2048, 256, 0, stream>>>(x4, n4, 8, 4096, 1, &st[10], fb2, &st[3]);
        scan_select<<<1, 1024, 0, stream>>>(fb2, 4096, nullptr, 0, &st[11], 0u, &st[12], &st[13], &st[3], 1);
        hist_pass<<<2048, 256, 0, stream>>>(x4, n4, 0, 256, 2, &st[10], fb3, &st[3]);
        scan_select<<<1, 1024, 0, stream>>>(fb3, 256, nullptr, 0, &st[13], 0u, &st[14], &st[15], &st[3], 1);
        finalize_thr_fb<<<1, 1, 0, stream>>>(st, &st[3]);
        mask_kernel<<<2048, 256, 0, stream>>>((const float4*)x, (float4*)out, n4, st, &st[3]);
    } else {
        // small-ws standalone fallback: 3-pass radix + mask (ungated)
        unsigned* h1 = ws + 16;
        unsigned* h2 = ws + 16 + 4096;
        unsigned* h3 = ws + 16 + 8192;

        hipMemsetAsync(d_ws, 0, FB_WS_INTS * sizeof(unsigned), stream);

        hist_pass<<<2048, 256, 0, stream>>>(x4, n4, 20, 4096, 0, &ws[10], h1, nullptr);
        scan_select<<<1, 1024, 0, stream>>>(h1, 4096, nullptr, 0, nullptr, r, &ws[10], &ws[11], nullptr, 0);
        hist_pass<<<2048, 256, 0, stream>>>(x4, n4, 8, 4096, 1, &ws[10], h2, nullptr);
        scan_select<<<1, 1024, 0, stream>>>(h2, 4096, nullptr, 0, &ws[11], 0u, &ws[12], &ws[13], nullptr, 0);
        hist_pass<<<2048, 256, 0, stream>>>(x4, n4, 0, 256, 2, &ws[10], h3, nullptr);
        scan_select<<<1, 1024, 0, stream>>>(h3, 256, nullptr, 0, &ws[13], 0u, &ws[14], &ws[15], nullptr, 0);
        finalize_thr_fb<<<1, 1, 0, stream>>>(ws, nullptr);
        mask_kernel<<<2048, 256, 0, stream>>>((const float4*)x, (float4*)out, n4, ws, nullptr);
    }
}